// Round 2
// baseline (1135.954 us; speedup 1.0000x reference)
//
#include <hip/hip_runtime.h>

#define BB 4
#define SSZ 2048
#define DD 1024
#define DH 64
#define NN (BB*SSZ)          // 8192 rows total

// ---------------- ws layout (in floats) ----------------
// q [NN][DH], k [NN][DH], v [NN][DH], ctx [NN][DH], colsum [NN],
// vp [NN][DH], WoR [DH][DD], E [nb][SSZ][SSZ]
#define OFF_Q   ((size_t)0)
#define OFF_K   ((size_t)NN*DH)
#define OFF_V   ((size_t)2*NN*DH)
#define OFF_CTX ((size_t)3*NN*DH)
#define OFF_CS  ((size_t)4*NN*DH)
#define OFF_VP  (OFF_CS + NN)
#define OFF_WOR (OFF_VP + (size_t)NN*DH)
#define OFF_E   (OFF_WOR + (size_t)DH*DD)

// ---------------- projections: q/k/v = X @ W + b ----------------
// grid (NN/256, 8, 3), block 256. K split 8 ways -> atomicAdd partials.
#define P_KC 128
__global__ __launch_bounds__(256, 2) void proj_kernel(
    const float* __restrict__ Q, const float* __restrict__ K, const float* __restrict__ V,
    const float* __restrict__ Wq, const float* __restrict__ bq,
    const float* __restrict__ Wk, const float* __restrict__ bk,
    const float* __restrict__ Wv, const float* __restrict__ bv,
    float* __restrict__ qkv)
{
    const int mat = blockIdx.z;
    const float* X    = mat == 0 ? Q  : (mat == 1 ? K  : V);
    const float* W    = mat == 0 ? Wq : (mat == 1 ? Wk : Wv);
    const float* bias = mat == 0 ? bq : (mat == 1 ? bk : bv);
    float* out = qkv + (size_t)mat * NN * DH;

    const int tid  = threadIdx.x;
    const int row0 = blockIdx.x * 256;
    const int k0   = blockIdx.y * P_KC;

    __shared__ float Xs[256][33];   // +1 pad: conflict-free scalar reads

    float acc[DH];
    if (blockIdx.y == 0) {
        #pragma unroll
        for (int c = 0; c < DH; ++c) acc[c] = bias[c];
    } else {
        #pragma unroll
        for (int c = 0; c < DH; ++c) acc[c] = 0.f;
    }

    for (int kk0 = 0; kk0 < P_KC; kk0 += 32) {
        __syncthreads();
        // stage 256 rows x 32 cols, coalesced float4 reads
        #pragma unroll
        for (int i = 0; i < 8; ++i) {
            int f  = tid + i * 256;        // 0..2047
            int r  = f >> 3;
            int c4 = f & 7;
            float4 a = *(const float4*)&X[(size_t)(row0 + r) * DD + k0 + kk0 + c4 * 4];
            Xs[r][c4*4+0] = a.x; Xs[r][c4*4+1] = a.y;
            Xs[r][c4*4+2] = a.z; Xs[r][c4*4+3] = a.w;
        }
        __syncthreads();
        #pragma unroll 4
        for (int kk = 0; kk < 32; ++kk) {
            const float a = Xs[tid][kk];
            const float* w = &W[(size_t)(k0 + kk0 + kk) * DH];   // wave-uniform -> s_load
            #pragma unroll
            for (int c = 0; c < DH; ++c) acc[c] += a * w[c];
        }
    }
    float* orow = out + (size_t)(row0 + tid) * DH;
    #pragma unroll
    for (int c = 0; c < DH; ++c) atomicAdd(&orow[c], acc[c]);
}

// ---------------- WoR[d][m] = sum_h Wo[h*64+d][m] ----------------
__global__ __launch_bounds__(256) void wored_kernel(
    const float* __restrict__ Wo, float* __restrict__ WoR)
{
    int idx = blockIdx.x * 256 + threadIdx.x;   // 0..65535
    int d = idx >> 10;
    int m = idx & 1023;
    float s = 0.f;
    #pragma unroll
    for (int h = 0; h < 16; ++h) s += Wo[(size_t)(h * DH + d) * DD + m];
    WoR[idx] = s;
}

// ---------------- scores: E = exp(q.k/8), colsum += sum_q E ----------------
// grid (16,16,nbg), block 256, tile 128x128, micro 8x8.
__global__ __launch_bounds__(256, 2) void scores_kernel(
    const float* __restrict__ qv, const float* __restrict__ kv,
    float* __restrict__ E, float* __restrict__ colsum, int b0)
{
    const int b  = b0 + blockIdx.z;
    const int q0 = blockIdx.x * 128;
    const int k0 = blockIdx.y * 128;
    const int tid = threadIdx.x;
    const int tc = tid & 15, tr = tid >> 4;

    __shared__ float qs[128 * 64];
    __shared__ float ks[128 * 64];

    const float* qg = qv + ((size_t)b * SSZ + q0) * DH;
    const float* kg = kv + ((size_t)b * SSZ + k0) * DH;
    #pragma unroll
    for (int i = 0; i < 8; ++i) {
        int f = tid + i * 256;           // 0..2047
        int r = f >> 4, d4 = f & 15;
        int sw = (r >> 3) & 7;
        float4 a = *(const float4*)&qg[(size_t)r * DH + d4 * 4];
        *(float4*)&qs[r * 64 + ((d4 ^ sw) << 2)] = a;
        float4 c = *(const float4*)&kg[(size_t)r * DH + d4 * 4];
        *(float4*)&ks[r * 64 + ((d4 ^ sw) << 2)] = c;
    }
    __syncthreads();

    float acc[8][8];
    #pragma unroll
    for (int i = 0; i < 8; ++i)
        #pragma unroll
        for (int j = 0; j < 8; ++j) acc[i][j] = 0.f;

    for (int d0 = 0; d0 < 64; d0 += 4) {
        float4 qf[8], kf[8];
        #pragma unroll
        for (int i = 0; i < 8; ++i) {
            int r = tr * 8 + i;
            qf[i] = *(const float4*)&qs[r * 64 + ((((d0 >> 2)) ^ ((r >> 3) & 7)) << 2)];
        }
        #pragma unroll
        for (int j = 0; j < 8; ++j) {
            int r = tc * 8 + j;
            kf[j] = *(const float4*)&ks[r * 64 + ((((d0 >> 2)) ^ ((r >> 3) & 7)) << 2)];
        }
        #pragma unroll
        for (int i = 0; i < 8; ++i)
            #pragma unroll
            for (int j = 0; j < 8; ++j)
                acc[i][j] += qf[i].x * kf[j].x + qf[i].y * kf[j].y
                           + qf[i].z * kf[j].z + qf[i].w * kf[j].w;
    }

    // epilogue: exp(score/8) -> E, block-partial column sums -> atomicAdd
    float cs[8];
    #pragma unroll
    for (int j = 0; j < 8; ++j) cs[j] = 0.f;
    float* Eb = E + (size_t)blockIdx.z * SSZ * SSZ;   // local-batch E slab
    #pragma unroll
    for (int i = 0; i < 8; ++i) {
        float e[8];
        #pragma unroll
        for (int j = 0; j < 8; ++j) {
            e[j] = __expf(acc[i][j] * 0.125f);
            cs[j] += e[j];
        }
        float* dst = Eb + (size_t)(q0 + tr * 8 + i) * SSZ + k0 + tc * 8;
        *(float4*)&dst[0] = make_float4(e[0], e[1], e[2], e[3]);
        *(float4*)&dst[4] = make_float4(e[4], e[5], e[6], e[7]);
    }
    #pragma unroll
    for (int j = 0; j < 8; ++j)
        atomicAdd(&colsum[(size_t)b * SSZ + k0 + tc * 8 + j], cs[j]);
}

// ---------------- vp = v / colsum ----------------
__global__ __launch_bounds__(256) void vprime_kernel(
    const float* __restrict__ v, const float* __restrict__ colsum,
    float* __restrict__ vp, int b0)
{
    int idx = blockIdx.x * 256 + threadIdx.x;        // < nbg*SSZ*DH
    int lb  = idx / (SSZ * DH);
    int rem = idx - lb * (SSZ * DH);
    size_t g = (size_t)(b0 + lb) * SSZ * DH + rem;
    vp[g] = v[g] / colsum[(size_t)(b0 + lb) * SSZ + (rem >> 6)];
}

// ---------------- ctx = E @ vp (per batch), K-split + atomics ----------------
// grid (16, 8, nbg), block 256, q-tile 128, per-block k-chunk 256, micro 8x4.
#define C_KC 256
__global__ __launch_bounds__(256, 2) void ctx_kernel(
    const float* __restrict__ E, const float* __restrict__ vp,
    float* __restrict__ ctx, int b0)
{
    const int lb = blockIdx.z;
    const int b  = b0 + lb;
    const int q0 = blockIdx.x * 128;
    const int kbase = blockIdx.y * C_KC;
    const int tid = threadIdx.x;
    const int tc = tid & 15, tr = tid >> 4;

    __shared__ float Es[128 * 128];   // 64 KB, XOR-swizzled

    const float* Eg  = E  + (size_t)lb * SSZ * SSZ;
    const float* vpg = vp + (size_t)b * SSZ * DH;

    float acc[8][4];
    #pragma unroll
    for (int i = 0; i < 8; ++i)
        #pragma unroll
        for (int j = 0; j < 4; ++j) acc[i][j] = 0.f;

    for (int kk0 = 0; kk0 < C_KC; kk0 += 128) {
        __syncthreads();
        #pragma unroll
        for (int i = 0; i < 16; ++i) {
            int f = tid + i * 256;        // 0..4095
            int r = f >> 5, c4 = f & 31;
            int sw = (r >> 3) & 7;
            float4 a = *(const float4*)&Eg[(size_t)(q0 + r) * SSZ + kbase + kk0 + c4 * 4];
            *(float4*)&Es[r * 128 + ((c4 ^ sw) << 2)] = a;
        }
        __syncthreads();
        for (int k = 0; k < 128; k += 4) {
            float vvf[4][4];
            #pragma unroll
            for (int dd = 0; dd < 4; ++dd) {
                float4 t = *(const float4*)&vpg[(size_t)(kbase + kk0 + k + dd) * DH + tc * 4];
                vvf[dd][0] = t.x; vvf[dd][1] = t.y; vvf[dd][2] = t.z; vvf[dd][3] = t.w;
            }
            #pragma unroll
            for (int i = 0; i < 8; ++i) {
                int r = tr * 8 + i;
                float4 e4 = *(const float4*)&Es[r * 128 + ((((k >> 2)) ^ ((r >> 3) & 7)) << 2)];
                #pragma unroll
                for (int j = 0; j < 4; ++j)
                    acc[i][j] += e4.x * vvf[0][j] + e4.y * vvf[1][j]
                               + e4.z * vvf[2][j] + e4.w * vvf[3][j];
            }
        }
    }
    float* cg = ctx + (size_t)b * SSZ * DH;
    #pragma unroll
    for (int i = 0; i < 8; ++i)
        #pragma unroll
        for (int j = 0; j < 4; ++j)
            atomicAdd(&cg[(size_t)(q0 + tr * 8 + i) * DH + tc * 4 + j], acc[i][j]);
}

// ---------------- out = ctx @ WoR + bo ----------------
// grid (NN/64, 4), block 256. tile 64 rows x 256 cols, micro 16x4.
__global__ __launch_bounds__(256, 2) void out_kernel(
    const float* __restrict__ ctx, const float* __restrict__ WoR,
    const float* __restrict__ bo, float* __restrict__ out)
{
    const int r0 = blockIdx.x * 64;
    const int c0 = blockIdx.y * 256;
    const int tid = threadIdx.x;
    const int cq  = tid & 63;      // cols c0 + cq*4 .. +3
    const int rid = tid >> 6;      // rows rid*16 + i

    __shared__ float ctxT[64][68];   // transposed [d][row], padded

    #pragma unroll
    for (int i = 0; i < 4; ++i) {
        int f = tid + i * 256;       // 0..1023
        int r = f >> 4, d4 = f & 15;
        float4 a = *(const float4*)&ctx[(size_t)(r0 + r) * DH + d4 * 4];
        ctxT[d4*4+0][r] = a.x; ctxT[d4*4+1][r] = a.y;
        ctxT[d4*4+2][r] = a.z; ctxT[d4*4+3][r] = a.w;
    }
    __syncthreads();

    float4 bias = *(const float4*)&bo[c0 + cq * 4];
    float acc[16][4];
    #pragma unroll
    for (int i = 0; i < 16; ++i) {
        acc[i][0] = bias.x; acc[i][1] = bias.y; acc[i][2] = bias.z; acc[i][3] = bias.w;
    }

    for (int d = 0; d < 64; ++d) {
        float4 w = *(const float4*)&WoR[(size_t)d * DD + c0 + cq * 4];
        #pragma unroll
        for (int ii = 0; ii < 4; ++ii) {
            float4 a4 = *(const float4*)&ctxT[d][rid * 16 + ii * 4];   // broadcast
            acc[ii*4+0][0] += a4.x * w.x; acc[ii*4+0][1] += a4.x * w.y;
            acc[ii*4+0][2] += a4.x * w.z; acc[ii*4+0][3] += a4.x * w.w;
            acc[ii*4+1][0] += a4.y * w.x; acc[ii*4+1][1] += a4.y * w.y;
            acc[ii*4+1][2] += a4.y * w.z; acc[ii*4+1][3] += a4.y * w.w;
            acc[ii*4+2][0] += a4.z * w.x; acc[ii*4+2][1] += a4.z * w.y;
            acc[ii*4+2][2] += a4.z * w.z; acc[ii*4+2][3] += a4.z * w.w;
            acc[ii*4+3][0] += a4.w * w.x; acc[ii*4+3][1] += a4.w * w.y;
            acc[ii*4+3][2] += a4.w * w.z; acc[ii*4+3][3] += a4.w * w.w;
        }
    }
    #pragma unroll
    for (int i = 0; i < 16; ++i)
        *(float4*)&out[(size_t)(r0 + rid * 16 + i) * DD + c0 + cq * 4] =
            make_float4(acc[i][0], acc[i][1], acc[i][2], acc[i][3]);
}

// ---------------- launch ----------------
extern "C" void kernel_launch(void* const* d_in, const int* in_sizes, int n_in,
                              void* d_out, int out_size, void* d_ws, size_t ws_size,
                              hipStream_t stream)
{
    const float* Q  = (const float*)d_in[0];
    const float* K  = (const float*)d_in[1];
    const float* V  = (const float*)d_in[2];
    const float* Wq = (const float*)d_in[3];
    const float* bq = (const float*)d_in[4];
    const float* Wk = (const float*)d_in[5];
    const float* bk = (const float*)d_in[6];
    const float* Wv = (const float*)d_in[7];
    const float* bv = (const float*)d_in[8];
    const float* Wo = (const float*)d_in[9];
    const float* bo = (const float*)d_in[10];
    float* out = (float*)d_out;

    float* ws = (float*)d_ws;
    float* qv     = ws + OFF_Q;
    float* kv     = ws + OFF_K;
    float* vv     = ws + OFF_V;
    float* ctx    = ws + OFF_CTX;
    float* colsum = ws + OFF_CS;
    float* vp     = ws + OFF_VP;
    float* WoR    = ws + OFF_WOR;
    float* E      = ws + OFF_E;

    // how many batches of E fit in the remaining workspace (fallback chunking)
    size_t wsf = ws_size / 4;
    int nb = 1;
    if (wsf > OFF_E) {
        size_t fit = (wsf - OFF_E) / ((size_t)SSZ * SSZ);
        nb = fit >= 4 ? 4 : (fit >= 1 ? (int)fit : 1);
    }

    // zero q,k,v,ctx (atomic accumulators) and colsum
    hipMemsetAsync(d_ws, 0, (size_t)(4 * (size_t)NN * DH + NN) * sizeof(float), stream);

    proj_kernel<<<dim3(NN / 256, 8, 3), 256, 0, stream>>>(Q, K, V, Wq, bq, Wk, bk, Wv, bv, qv);
    wored_kernel<<<dim3((DH * DD) / 256), 256, 0, stream>>>(Wo, WoR);

    for (int b0 = 0; b0 < BB; b0 += nb) {
        int nbg = (BB - b0) < nb ? (BB - b0) : nb;
        scores_kernel<<<dim3(16, 16, nbg), 256, 0, stream>>>(qv, kv, E, colsum, b0);
        vprime_kernel<<<dim3(nbg * (SSZ * DH / 256)), 256, 0, stream>>>(vv, colsum, vp, b0);
        ctx_kernel<<<dim3(16, 8, nbg), 256, 0, stream>>>(E, vp, ctx, b0);
    }
    out_kernel<<<dim3(NN / 64, 4), 256, 0, stream>>>(ctx, WoR, bo, out);
}

// Round 8
// 482.593 us; speedup vs baseline: 2.3539x; 2.3539x over previous
//
#include <hip/hip_runtime.h>

#define BB 4
#define SSZ 2048
#define DD 1024
#define DH 64
#define NN (BB*SSZ)          // 8192 rows total
#define NSPLIT 4             // ctx split-K partial slabs

// ---------------- ws layout (in floats) ----------------
// q [NN][DH], k [NN][DH], v [NN][DH], ctxp [NSPLIT][NN][DH], colsum [NN],
// vp [NN][DH], WoR [DH][DD], E [nb][SSZ][SSZ]
#define OFF_Q    ((size_t)0)
#define OFF_K    ((size_t)NN*DH)
#define OFF_V    ((size_t)2*NN*DH)
#define OFF_CTXP ((size_t)3*NN*DH)
#define OFF_CS   (OFF_CTXP + (size_t)NSPLIT*NN*DH)
#define OFF_VP   (OFF_CS + NN)
#define OFF_WOR  (OFF_VP + (size_t)NN*DH)
#define OFF_E    (OFF_WOR + (size_t)DH*DD)

// NOTE: parameter names must NOT collide with float4 member names (x,y,z,w) --
// the preprocessor substitutes params in member-access position too.
#define FMA4(A_, S_, W_) \
    A_.x += (S_) * (W_).x; A_.y += (S_) * (W_).y; \
    A_.z += (S_) * (W_).z; A_.w += (S_) * (W_).w;

// ---------------- projections: q/k/v = X @ W + b ----------------
// grid (NN/64, 3), block 256. Tile 64 rows x 64 cols, FULL K (no atomics).
__global__ __launch_bounds__(256) void proj_kernel(
    const float* __restrict__ Q, const float* __restrict__ K, const float* __restrict__ V,
    const float* __restrict__ Wq, const float* __restrict__ bq,
    const float* __restrict__ Wk, const float* __restrict__ bk,
    const float* __restrict__ Wv, const float* __restrict__ bv,
    float* __restrict__ qkv)
{
    const int mat = blockIdx.y;
    const float* X    = mat == 0 ? Q  : (mat == 1 ? K  : V);
    const float* W    = mat == 0 ? Wq : (mat == 1 ? Wk : Wv);
    const float* bias = mat == 0 ? bq : (mat == 1 ? bk : bv);
    float* out = qkv + (size_t)mat * NN * DH;

    const int tid  = threadIdx.x;
    const int row0 = blockIdx.x * 64;
    const int tc = tid & 15;   // cols tc*4 .. +3
    const int tr = tid >> 4;   // rows tr*4 .. +3

    __shared__ float Xs[64 * 36];   // 64 rows x 32 k, stride 36
    __shared__ float Ws[32 * 64];   // 32 k x 64 cols

    float4 bias4 = *(const float4*)&bias[tc * 4];
    float4 acc[4];
    #pragma unroll
    for (int i = 0; i < 4; ++i) acc[i] = bias4;

    for (int k0 = 0; k0 < DD; k0 += 32) {
        __syncthreads();
        #pragma unroll
        for (int i = 0; i < 2; ++i) {
            int f = tid + i * 256;          // 0..511 float4 ids
            int r = f >> 3, c4 = f & 7;     // 8 float4 per 32-k row
            float4 a = *(const float4*)&X[(size_t)(row0 + r) * DD + k0 + c4 * 4];
            *(float4*)&Xs[r * 36 + c4 * 4] = a;
        }
        #pragma unroll
        for (int i = 0; i < 2; ++i) {
            int f = tid + i * 256;
            int r = f >> 4, c4 = f & 15;    // 16 float4 per 64-col row
            float4 a = *(const float4*)&W[(size_t)(k0 + r) * DH + c4 * 4];
            *(float4*)&Ws[r * 64 + c4 * 4] = a;
        }
        __syncthreads();
        #pragma unroll
        for (int kg = 0; kg < 32; kg += 4) {
            float4 xv0 = *(const float4*)&Xs[(tr * 4 + 0) * 36 + kg];
            float4 xv1 = *(const float4*)&Xs[(tr * 4 + 1) * 36 + kg];
            float4 xv2 = *(const float4*)&Xs[(tr * 4 + 2) * 36 + kg];
            float4 xv3 = *(const float4*)&Xs[(tr * 4 + 3) * 36 + kg];
            float4 w0 = *(const float4*)&Ws[(kg + 0) * 64 + tc * 4];
            float4 w1 = *(const float4*)&Ws[(kg + 1) * 64 + tc * 4];
            float4 w2 = *(const float4*)&Ws[(kg + 2) * 64 + tc * 4];
            float4 w3 = *(const float4*)&Ws[(kg + 3) * 64 + tc * 4];
            FMA4(acc[0], xv0.x, w0); FMA4(acc[0], xv0.y, w1);
            FMA4(acc[0], xv0.z, w2); FMA4(acc[0], xv0.w, w3);
            FMA4(acc[1], xv1.x, w0); FMA4(acc[1], xv1.y, w1);
            FMA4(acc[1], xv1.z, w2); FMA4(acc[1], xv1.w, w3);
            FMA4(acc[2], xv2.x, w0); FMA4(acc[2], xv2.y, w1);
            FMA4(acc[2], xv2.z, w2); FMA4(acc[2], xv2.w, w3);
            FMA4(acc[3], xv3.x, w0); FMA4(acc[3], xv3.y, w1);
            FMA4(acc[3], xv3.z, w2); FMA4(acc[3], xv3.w, w3);
        }
    }
    #pragma unroll
    for (int i = 0; i < 4; ++i)
        *(float4*)&out[(size_t)(row0 + tr * 4 + i) * DH + tc * 4] = acc[i];
}

// ---------------- WoR[d][m] = sum_h Wo[h*64+d][m] ----------------
__global__ __launch_bounds__(256) void wored_kernel(
    const float* __restrict__ Wo, float* __restrict__ WoR)
{
    int idx = blockIdx.x * 256 + threadIdx.x;   // 0..65535
    int d = idx >> 10;
    int m = idx & 1023;
    float s = 0.f;
    #pragma unroll
    for (int h = 0; h < 16; ++h) s += Wo[(size_t)(h * DH + d) * DD + m];
    WoR[idx] = s;
}

// ---------------- scores: E = exp(q.k/8), colsum += sum_q E ----------------
// grid (16,16,nbg), block 256, tile 128x128, micro 8x8.
__global__ __launch_bounds__(256, 2) void scores_kernel(
    const float* __restrict__ qv, const float* __restrict__ kv,
    float* __restrict__ E, float* __restrict__ colsum, int b0)
{
    const int b  = b0 + blockIdx.z;
    const int q0 = blockIdx.x * 128;
    const int k0 = blockIdx.y * 128;
    const int tid = threadIdx.x;
    const int tc = tid & 15, tr = tid >> 4;

    __shared__ float qs[128 * 64];
    __shared__ float ks[128 * 64];

    const float* qg = qv + ((size_t)b * SSZ + q0) * DH;
    const float* kg = kv + ((size_t)b * SSZ + k0) * DH;
    #pragma unroll
    for (int i = 0; i < 8; ++i) {
        int f = tid + i * 256;           // 0..2047
        int r = f >> 4, d4 = f & 15;
        int sw = (r >> 3) & 7;
        float4 a = *(const float4*)&qg[(size_t)r * DH + d4 * 4];
        *(float4*)&qs[r * 64 + ((d4 ^ sw) << 2)] = a;
        float4 c = *(const float4*)&kg[(size_t)r * DH + d4 * 4];
        *(float4*)&ks[r * 64 + ((d4 ^ sw) << 2)] = c;
    }
    __syncthreads();

    float acc[8][8];
    #pragma unroll
    for (int i = 0; i < 8; ++i)
        #pragma unroll
        for (int j = 0; j < 8; ++j) acc[i][j] = 0.f;

    for (int d0 = 0; d0 < 64; d0 += 4) {
        float4 qf[8], kf[8];
        #pragma unroll
        for (int i = 0; i < 8; ++i) {
            int r = tr * 8 + i;
            qf[i] = *(const float4*)&qs[r * 64 + ((((d0 >> 2)) ^ ((r >> 3) & 7)) << 2)];
        }
        #pragma unroll
        for (int j = 0; j < 8; ++j) {
            int r = tc * 8 + j;
            kf[j] = *(const float4*)&ks[r * 64 + ((((d0 >> 2)) ^ ((r >> 3) & 7)) << 2)];
        }
        #pragma unroll
        for (int i = 0; i < 8; ++i)
            #pragma unroll
            for (int j = 0; j < 8; ++j)
                acc[i][j] += qf[i].x * kf[j].x + qf[i].y * kf[j].y
                           + qf[i].z * kf[j].z + qf[i].w * kf[j].w;
    }

    // epilogue: exp(score/8) -> E, block-partial column sums -> atomicAdd
    float cs[8];
    #pragma unroll
    for (int j = 0; j < 8; ++j) cs[j] = 0.f;
    float* Eb = E + (size_t)blockIdx.z * SSZ * SSZ;   // local-batch E slab
    #pragma unroll
    for (int i = 0; i < 8; ++i) {
        float e[8];
        #pragma unroll
        for (int j = 0; j < 8; ++j) {
            e[j] = __expf(acc[i][j] * 0.125f);
            cs[j] += e[j];
        }
        float* dst = Eb + (size_t)(q0 + tr * 8 + i) * SSZ + k0 + tc * 8;
        *(float4*)&dst[0] = make_float4(e[0], e[1], e[2], e[3]);
        *(float4*)&dst[4] = make_float4(e[4], e[5], e[6], e[7]);
    }
    #pragma unroll
    for (int j = 0; j < 8; ++j)
        atomicAdd(&colsum[(size_t)b * SSZ + k0 + tc * 8 + j], cs[j]);
}

// ---------------- vp = v / colsum ----------------
__global__ __launch_bounds__(256) void vprime_kernel(
    const float* __restrict__ v, const float* __restrict__ colsum,
    float* __restrict__ vp, int b0)
{
    int idx = blockIdx.x * 256 + threadIdx.x;        // < nbg*SSZ*DH
    int lb  = idx / (SSZ * DH);
    int rem = idx - lb * (SSZ * DH);
    size_t g = (size_t)(b0 + lb) * SSZ * DH + rem;
    vp[g] = v[g] / colsum[(size_t)(b0 + lb) * SSZ + (rem >> 6)];
}

// ---------------- ctx partials: ctxp[s] = E[:, s-chunk] @ vp[s-chunk] ----------------
// grid (16, NSPLIT, nbg), block 256, q-tile 128, k-chunk 512, micro 8x4.
// Plain stores to per-split slabs -- NO atomics.
#define C_KC (SSZ / NSPLIT)   // 512
__global__ __launch_bounds__(256, 2) void ctx_kernel(
    const float* __restrict__ E, const float* __restrict__ vp,
    float* __restrict__ ctxp, int b0)
{
    const int lb = blockIdx.z;
    const int b  = b0 + lb;
    const int split = blockIdx.y;
    const int q0 = blockIdx.x * 128;
    const int kbase = split * C_KC;
    const int tid = threadIdx.x;
    const int tc = tid & 15, tr = tid >> 4;

    __shared__ float Es[128 * 128];   // 64 KB, XOR-swizzled

    const float* Eg  = E  + (size_t)lb * SSZ * SSZ;
    const float* vpg = vp + (size_t)b * SSZ * DH;

    float acc[8][4];
    #pragma unroll
    for (int i = 0; i < 8; ++i)
        #pragma unroll
        for (int j = 0; j < 4; ++j) acc[i][j] = 0.f;

    for (int kk0 = 0; kk0 < C_KC; kk0 += 128) {
        __syncthreads();
        #pragma unroll
        for (int i = 0; i < 16; ++i) {
            int f = tid + i * 256;        // 0..4095
            int r = f >> 5, c4 = f & 31;
            int sw = (r >> 3) & 7;
            float4 a = *(const float4*)&Eg[(size_t)(q0 + r) * SSZ + kbase + kk0 + c4 * 4];
            *(float4*)&Es[r * 128 + ((c4 ^ sw) << 2)] = a;
        }
        __syncthreads();
        for (int k = 0; k < 128; k += 4) {
            float vvf[4][4];
            #pragma unroll
            for (int dd = 0; dd < 4; ++dd) {
                float4 t = *(const float4*)&vpg[(size_t)(kbase + kk0 + k + dd) * DH + tc * 4];
                vvf[dd][0] = t.x; vvf[dd][1] = t.y; vvf[dd][2] = t.z; vvf[dd][3] = t.w;
            }
            #pragma unroll
            for (int i = 0; i < 8; ++i) {
                int r = tr * 8 + i;
                float4 e4 = *(const float4*)&Es[r * 128 + ((((k >> 2)) ^ ((r >> 3) & 7)) << 2)];
                #pragma unroll
                for (int j = 0; j < 4; ++j)
                    acc[i][j] += e4.x * vvf[0][j] + e4.y * vvf[1][j]
                               + e4.z * vvf[2][j] + e4.w * vvf[3][j];
            }
        }
    }
    float* cg = ctxp + (size_t)split * NN * DH + (size_t)b * SSZ * DH;
    #pragma unroll
    for (int i = 0; i < 8; ++i)
        *(float4*)&cg[(size_t)(q0 + tr * 8 + i) * DH + tc * 4] =
            make_float4(acc[i][0], acc[i][1], acc[i][2], acc[i][3]);
}

// ---------------- out = (sum_s ctxp[s]) @ WoR + bo ----------------
// grid (NN/64, 4), block 256. tile 64 rows x 256 cols, micro 16x4.
__global__ __launch_bounds__(256, 2) void out_kernel(
    const float* __restrict__ ctxp, const float* __restrict__ WoR,
    const float* __restrict__ bo, float* __restrict__ out)
{
    const int r0 = blockIdx.x * 64;
    const int c0 = blockIdx.y * 256;
    const int tid = threadIdx.x;
    const int cq  = tid & 63;      // cols c0 + cq*4 .. +3
    const int rid = tid >> 6;      // rows rid*16 + i

    __shared__ float ctxT[64][68];   // transposed [d][row], padded

    #pragma unroll
    for (int i = 0; i < 4; ++i) {
        int f = tid + i * 256;       // 0..1023
        int r = f >> 4, d4 = f & 15;
        size_t base = (size_t)(r0 + r) * DH + d4 * 4;
        float4 a = *(const float4*)&ctxp[base];
        #pragma unroll
        for (int s = 1; s < NSPLIT; ++s) {
            float4 p = *(const float4*)&ctxp[(size_t)s * NN * DH + base];
            a.x += p.x; a.y += p.y; a.z += p.z; a.w += p.w;
        }
        ctxT[d4*4+0][r] = a.x; ctxT[d4*4+1][r] = a.y;
        ctxT[d4*4+2][r] = a.z; ctxT[d4*4+3][r] = a.w;
    }
    __syncthreads();

    float4 bias = *(const float4*)&bo[c0 + cq * 4];
    float acc[16][4];
    #pragma unroll
    for (int i = 0; i < 16; ++i) {
        acc[i][0] = bias.x; acc[i][1] = bias.y; acc[i][2] = bias.z; acc[i][3] = bias.w;
    }

    for (int d = 0; d < 64; ++d) {
        float4 w4 = *(const float4*)&WoR[(size_t)d * DD + c0 + cq * 4];
        #pragma unroll
        for (int ii = 0; ii < 4; ++ii) {
            float4 a4 = *(const float4*)&ctxT[d][rid * 16 + ii * 4];   // broadcast
            acc[ii*4+0][0] += a4.x * w4.x; acc[ii*4+0][1] += a4.x * w4.y;
            acc[ii*4+0][2] += a4.x * w4.z; acc[ii*4+0][3] += a4.x * w4.w;
            acc[ii*4+1][0] += a4.y * w4.x; acc[ii*4+1][1] += a4.y * w4.y;
            acc[ii*4+1][2] += a4.y * w4.z; acc[ii*4+1][3] += a4.y * w4.w;
            acc[ii*4+2][0] += a4.z * w4.x; acc[ii*4+2][1] += a4.z * w4.y;
            acc[ii*4+2][2] += a4.z * w4.z; acc[ii*4+2][3] += a4.z * w4.w;
            acc[ii*4+3][0] += a4.w * w4.x; acc[ii*4+3][1] += a4.w * w4.y;
            acc[ii*4+3][2] += a4.w * w4.z; acc[ii*4+3][3] += a4.w * w4.w;
        }
    }
    #pragma unroll
    for (int i = 0; i < 16; ++i)
        *(float4*)&out[(size_t)(r0 + rid * 16 + i) * DD + c0 + cq * 4] =
            make_float4(acc[i][0], acc[i][1], acc[i][2], acc[i][3]);
}

// ---------------- launch ----------------
extern "C" void kernel_launch(void* const* d_in, const int* in_sizes, int n_in,
                              void* d_out, int out_size, void* d_ws, size_t ws_size,
                              hipStream_t stream)
{
    const float* Q  = (const float*)d_in[0];
    const float* K  = (const float*)d_in[1];
    const float* V  = (const float*)d_in[2];
    const float* Wq = (const float*)d_in[3];
    const float* bq = (const float*)d_in[4];
    const float* Wk = (const float*)d_in[5];
    const float* bk = (const float*)d_in[6];
    const float* Wv = (const float*)d_in[7];
    const float* bv = (const float*)d_in[8];
    const float* Wo = (const float*)d_in[9];
    const float* bo = (const float*)d_in[10];
    float* out = (float*)d_out;

    float* ws = (float*)d_ws;
    float* qv     = ws + OFF_Q;
    float* kv     = ws + OFF_K;
    float* vv     = ws + OFF_V;
    float* ctxp   = ws + OFF_CTXP;
    float* colsum = ws + OFF_CS;
    float* vp     = ws + OFF_VP;
    float* WoR    = ws + OFF_WOR;
    float* E      = ws + OFF_E;

    // how many batches of E fit in the remaining workspace (fallback chunking)
    size_t wsf = ws_size / 4;
    int nb = 1;
    if (wsf > OFF_E) {
        size_t fit = (wsf - OFF_E) / ((size_t)SSZ * SSZ);
        nb = fit >= 4 ? 4 : (fit >= 1 ? (int)fit : 1);
    }

    // zero ONLY the colsum atomic accumulator
    hipMemsetAsync(colsum, 0, (size_t)NN * sizeof(float), stream);

    proj_kernel<<<dim3(NN / 64, 3), 256, 0, stream>>>(Q, K, V, Wq, bq, Wk, bk, Wv, bv, qv);
    wored_kernel<<<dim3((DH * DD) / 256), 256, 0, stream>>>(Wo, WoR);

    for (int b0 = 0; b0 < BB; b0 += nb) {
        int nbg = (BB - b0) < nb ? (BB - b0) : nb;
        scores_kernel<<<dim3(16, 16, nbg), 256, 0, stream>>>(qv, kv, E, colsum, b0);
        vprime_kernel<<<dim3(nbg * (SSZ * DH / 256)), 256, 0, stream>>>(vv, colsum, vp, b0);
        ctx_kernel<<<dim3(16, NSPLIT, nbg), 256, 0, stream>>>(E, vp, ctxp, b0);
    }
    out_kernel<<<dim3(NN / 64, 4), 256, 0, stream>>>(ctxp, WoR, bo, out);
}

// Round 13
// 328.845 us; speedup vs baseline: 3.4544x; 1.4675x over previous
//
#include <hip/hip_runtime.h>

#define BB 4
#define SSZ 2048
#define DD 1024
#define DH 64
#define NN (BB*SSZ)          // 8192 rows total
#define NSPLIT 4             // ctx split-K partial slabs
#define NQB 16               // q-blocks in scores (SSZ/128)

// ---------------- ws layout (in floats) ----------------
// q [NN][DH], k [NN][DH], v [NN][DH], ctxp [NSPLIT][NN][DH], colsum [NN],
// colsum_p [NQB][BB][SSZ], vp [NN][DH], WoR [DH][DD], E [nb][SSZ][SSZ]
#define OFF_Q    ((size_t)0)
#define OFF_K    ((size_t)NN*DH)
#define OFF_V    ((size_t)2*NN*DH)
#define OFF_CTXP ((size_t)3*NN*DH)
#define OFF_CS   (OFF_CTXP + (size_t)NSPLIT*NN*DH)
#define OFF_CSP  (OFF_CS + NN)
#define OFF_VP   (OFF_CSP + (size_t)NQB*BB*SSZ)
#define OFF_WOR  (OFF_VP + (size_t)NN*DH)
#define OFF_E    (OFF_WOR + (size_t)DH*DD)

// NOTE: parameter names must NOT collide with float4 member names (x,y,z,w) --
// the preprocessor substitutes params in member-access position too.
#define FMA4(A_, S_, W_) \
    A_.x += (S_) * (W_).x; A_.y += (S_) * (W_).y; \
    A_.z += (S_) * (W_).z; A_.w += (S_) * (W_).w;

// ---------------- projections: q/k/v = X @ W + b ----------------
// grid (NN/64, 3), block 256. Tile 64 rows x 64 cols, FULL K (no atomics).
__global__ __launch_bounds__(256) void proj_kernel(
    const float* __restrict__ Q, const float* __restrict__ K, const float* __restrict__ V,
    const float* __restrict__ Wq, const float* __restrict__ bq,
    const float* __restrict__ Wk, const float* __restrict__ bk,
    const float* __restrict__ Wv, const float* __restrict__ bv,
    float* __restrict__ qkv)
{
    const int mat = blockIdx.y;
    const float* X    = mat == 0 ? Q  : (mat == 1 ? K  : V);
    const float* W    = mat == 0 ? Wq : (mat == 1 ? Wk : Wv);
    const float* bias = mat == 0 ? bq : (mat == 1 ? bk : bv);
    float* out = qkv + (size_t)mat * NN * DH;

    const int tid  = threadIdx.x;
    const int row0 = blockIdx.x * 64;
    const int tc = tid & 15;   // cols tc*4 .. +3
    const int tr = tid >> 4;   // rows tr*4 .. +3

    __shared__ float Xs[64 * 36];   // 64 rows x 32 k, stride 36
    __shared__ float Ws[32 * 64];   // 32 k x 64 cols

    float4 bias4 = *(const float4*)&bias[tc * 4];
    float4 acc[4];
    #pragma unroll
    for (int i = 0; i < 4; ++i) acc[i] = bias4;

    for (int k0 = 0; k0 < DD; k0 += 32) {
        __syncthreads();
        #pragma unroll
        for (int i = 0; i < 2; ++i) {
            int f = tid + i * 256;          // 0..511 float4 ids
            int r = f >> 3, c4 = f & 7;     // 8 float4 per 32-k row
            float4 a = *(const float4*)&X[(size_t)(row0 + r) * DD + k0 + c4 * 4];
            *(float4*)&Xs[r * 36 + c4 * 4] = a;
        }
        #pragma unroll
        for (int i = 0; i < 2; ++i) {
            int f = tid + i * 256;
            int r = f >> 4, c4 = f & 15;    // 16 float4 per 64-col row
            float4 a = *(const float4*)&W[(size_t)(k0 + r) * DH + c4 * 4];
            *(float4*)&Ws[r * 64 + c4 * 4] = a;
        }
        __syncthreads();
        #pragma unroll
        for (int kg = 0; kg < 32; kg += 4) {
            float4 xv0 = *(const float4*)&Xs[(tr * 4 + 0) * 36 + kg];
            float4 xv1 = *(const float4*)&Xs[(tr * 4 + 1) * 36 + kg];
            float4 xv2 = *(const float4*)&Xs[(tr * 4 + 2) * 36 + kg];
            float4 xv3 = *(const float4*)&Xs[(tr * 4 + 3) * 36 + kg];
            float4 w0 = *(const float4*)&Ws[(kg + 0) * 64 + tc * 4];
            float4 w1 = *(const float4*)&Ws[(kg + 1) * 64 + tc * 4];
            float4 w2 = *(const float4*)&Ws[(kg + 2) * 64 + tc * 4];
            float4 w3 = *(const float4*)&Ws[(kg + 3) * 64 + tc * 4];
            FMA4(acc[0], xv0.x, w0); FMA4(acc[0], xv0.y, w1);
            FMA4(acc[0], xv0.z, w2); FMA4(acc[0], xv0.w, w3);
            FMA4(acc[1], xv1.x, w0); FMA4(acc[1], xv1.y, w1);
            FMA4(acc[1], xv1.z, w2); FMA4(acc[1], xv1.w, w3);
            FMA4(acc[2], xv2.x, w0); FMA4(acc[2], xv2.y, w1);
            FMA4(acc[2], xv2.z, w2); FMA4(acc[2], xv2.w, w3);
            FMA4(acc[3], xv3.x, w0); FMA4(acc[3], xv3.y, w1);
            FMA4(acc[3], xv3.z, w2); FMA4(acc[3], xv3.w, w3);
        }
    }
    #pragma unroll
    for (int i = 0; i < 4; ++i)
        *(float4*)&out[(size_t)(row0 + tr * 4 + i) * DH + tc * 4] = acc[i];
}

// ---------------- WoR[d][m] = sum_h Wo[h*64+d][m] ----------------
__global__ __launch_bounds__(256) void wored_kernel(
    const float* __restrict__ Wo, float* __restrict__ WoR)
{
    int idx = blockIdx.x * 256 + threadIdx.x;   // 0..65535
    int d = idx >> 10;
    int m = idx & 1023;
    float s = 0.f;
    #pragma unroll
    for (int h = 0; h < 16; ++h) s += Wo[(size_t)(h * DH + d) * DD + m];
    WoR[idx] = s;
}

// ---------------- scores: E = exp(q.k/8), per-block colsum partials ----------------
// grid (NQB,16,nbg), block 256, tile 128x128, micro 8x(4+4).
// Lane owns cols tc*4+{0..3} and 64+tc*4+{0..3}: both E stores are
// lane-contiguous 256B runs (full-sector writes). NO atomics: per-thread
// column sums -> LDS reduce over the 16 row-groups -> one store per column.
__global__ __launch_bounds__(256, 2) void scores_kernel(
    const float* __restrict__ qv, const float* __restrict__ kv,
    float* __restrict__ E, float* __restrict__ colsum_p, int b0)
{
    const int b  = b0 + blockIdx.z;
    const int qb = blockIdx.x;
    const int q0 = qb * 128;
    const int k0 = blockIdx.y * 128;
    const int tid = threadIdx.x;
    const int tc = tid & 15, tr = tid >> 4;

    __shared__ float qs[128 * 64];
    __shared__ float ks[128 * 64];

    const float* qg = qv + ((size_t)b * SSZ + q0) * DH;
    const float* kg = kv + ((size_t)b * SSZ + k0) * DH;
    #pragma unroll
    for (int i = 0; i < 8; ++i) {
        int f = tid + i * 256;           // 0..2047
        int r = f >> 4, d4 = f & 15;
        int sw = (r >> 3) & 7;
        float4 a = *(const float4*)&qg[(size_t)r * DH + d4 * 4];
        *(float4*)&qs[r * 64 + ((d4 ^ sw) << 2)] = a;
        float4 c = *(const float4*)&kg[(size_t)r * DH + d4 * 4];
        *(float4*)&ks[r * 64 + ((d4 ^ sw) << 2)] = c;
    }
    __syncthreads();

    float acc[8][8];
    #pragma unroll
    for (int i = 0; i < 8; ++i)
        #pragma unroll
        for (int j = 0; j < 8; ++j) acc[i][j] = 0.f;

    for (int d0 = 0; d0 < 64; d0 += 4) {
        float4 qf[8], kf[8];
        #pragma unroll
        for (int i = 0; i < 8; ++i) {
            int r = tr * 8 + i;
            qf[i] = *(const float4*)&qs[r * 64 + ((((d0 >> 2)) ^ ((r >> 3) & 7)) << 2)];
        }
        #pragma unroll
        for (int j = 0; j < 8; ++j) {
            int r = (j < 4) ? (tc * 4 + j) : (64 + tc * 4 + (j - 4));   // owned col
            kf[j] = *(const float4*)&ks[r * 64 + ((((d0 >> 2)) ^ ((r >> 3) & 7)) << 2)];
        }
        #pragma unroll
        for (int i = 0; i < 8; ++i)
            #pragma unroll
            for (int j = 0; j < 8; ++j)
                acc[i][j] += qf[i].x * kf[j].x + qf[i].y * kf[j].y
                           + qf[i].z * kf[j].z + qf[i].w * kf[j].w;
    }

    // epilogue: exp(score/8) -> E (coalesced), per-thread column sums
    float cs[8];
    #pragma unroll
    for (int j = 0; j < 8; ++j) cs[j] = 0.f;
    float* Eb = E + (size_t)blockIdx.z * SSZ * SSZ;   // local-batch E slab
    #pragma unroll
    for (int i = 0; i < 8; ++i) {
        float e[8];
        #pragma unroll
        for (int j = 0; j < 8; ++j) {
            e[j] = __expf(acc[i][j] * 0.125f);
            cs[j] += e[j];
        }
        float* dst = Eb + (size_t)(q0 + tr * 8 + i) * SSZ + k0;
        *(float4*)&dst[tc * 4]      = make_float4(e[0], e[1], e[2], e[3]);
        *(float4*)&dst[64 + tc * 4] = make_float4(e[4], e[5], e[6], e[7]);
    }

    // LDS reduce cs over the 16 tr-groups -> one plain store per column
    __syncthreads();                       // everyone done reading qs
    float* red = qs;                       // reuse: [16][132] padded
    #pragma unroll
    for (int j = 0; j < 8; ++j) {
        int c = (j < 4) ? (tc * 4 + j) : (64 + tc * 4 + (j - 4));
        red[tr * 132 + c] = cs[j];
    }
    __syncthreads();
    if (tid < 128) {
        float s = 0.f;
        #pragma unroll
        for (int t = 0; t < 16; ++t) s += red[t * 132 + tid];
        colsum_p[((size_t)qb * BB + b) * SSZ + k0 + tid] = s;
    }
}

// ---------------- colsum[b][s] = sum_qb colsum_p[qb][b][s] ----------------
__global__ __launch_bounds__(256) void colsum_reduce_kernel(
    const float* __restrict__ colsum_p, float* __restrict__ colsum, int b0)
{
    int idx = blockIdx.x * 256 + threadIdx.x;   // < nbg*SSZ
    int lb = idx / SSZ;
    int s  = idx - lb * SSZ;
    int b  = b0 + lb;
    float sum = 0.f;
    #pragma unroll
    for (int qb = 0; qb < NQB; ++qb)
        sum += colsum_p[((size_t)qb * BB + b) * SSZ + s];
    colsum[(size_t)b * SSZ + s] = sum;
}

// ---------------- vp = v / colsum ----------------
__global__ __launch_bounds__(256) void vprime_kernel(
    const float* __restrict__ v, const float* __restrict__ colsum,
    float* __restrict__ vp, int b0)
{
    int idx = blockIdx.x * 256 + threadIdx.x;        // < nbg*SSZ*DH
    int lb  = idx / (SSZ * DH);
    int rem = idx - lb * (SSZ * DH);
    size_t g = (size_t)(b0 + lb) * SSZ * DH + rem;
    vp[g] = v[g] / colsum[(size_t)(b0 + lb) * SSZ + (rem >> 6)];
}

// ---------------- ctx partials: ctxp[s] = E[:, s-chunk] @ vp[s-chunk] ----------------
// grid (16, NSPLIT, nbg), block 256, q-tile 128, k-chunk 512, micro 8x4.
// Plain stores to per-split slabs -- NO atomics.
#define C_KC (SSZ / NSPLIT)   // 512
__global__ __launch_bounds__(256, 2) void ctx_kernel(
    const float* __restrict__ E, const float* __restrict__ vp,
    float* __restrict__ ctxp, int b0)
{
    const int lb = blockIdx.z;
    const int b  = b0 + lb;
    const int split = blockIdx.y;
    const int q0 = blockIdx.x * 128;
    const int kbase = split * C_KC;
    const int tid = threadIdx.x;
    const int tc = tid & 15, tr = tid >> 4;

    __shared__ float Es[128 * 128];   // 64 KB, XOR-swizzled

    const float* Eg  = E  + (size_t)lb * SSZ * SSZ;
    const float* vpg = vp + (size_t)b * SSZ * DH;

    float acc[8][4];
    #pragma unroll
    for (int i = 0; i < 8; ++i)
        #pragma unroll
        for (int j = 0; j < 4; ++j) acc[i][j] = 0.f;

    for (int kk0 = 0; kk0 < C_KC; kk0 += 128) {
        __syncthreads();
        #pragma unroll
        for (int i = 0; i < 16; ++i) {
            int f = tid + i * 256;        // 0..4095
            int r = f >> 5, c4 = f & 31;
            int sw = (r >> 3) & 7;
            float4 a = *(const float4*)&Eg[(size_t)(q0 + r) * SSZ + kbase + kk0 + c4 * 4];
            *(float4*)&Es[r * 128 + ((c4 ^ sw) << 2)] = a;
        }
        __syncthreads();
        for (int k = 0; k < 128; k += 4) {
            float vvf[4][4];
            #pragma unroll
            for (int dd = 0; dd < 4; ++dd) {
                float4 t = *(const float4*)&vpg[(size_t)(kbase + kk0 + k + dd) * DH + tc * 4];
                vvf[dd][0] = t.x; vvf[dd][1] = t.y; vvf[dd][2] = t.z; vvf[dd][3] = t.w;
            }
            #pragma unroll
            for (int i = 0; i < 8; ++i) {
                int r = tr * 8 + i;
                float4 e4 = *(const float4*)&Es[r * 128 + ((((k >> 2)) ^ ((r >> 3) & 7)) << 2)];
                #pragma unroll
                for (int j = 0; j < 4; ++j)
                    acc[i][j] += e4.x * vvf[0][j] + e4.y * vvf[1][j]
                               + e4.z * vvf[2][j] + e4.w * vvf[3][j];
            }
        }
    }
    float* cg = ctxp + (size_t)split * NN * DH + (size_t)b * SSZ * DH;
    #pragma unroll
    for (int i = 0; i < 8; ++i)
        *(float4*)&cg[(size_t)(q0 + tr * 8 + i) * DH + tc * 4] =
            make_float4(acc[i][0], acc[i][1], acc[i][2], acc[i][3]);
}

// ---------------- out = (sum_s ctxp[s]) @ WoR + bo ----------------
// grid (NN/64, 4), block 256. tile 64 rows x 256 cols, micro 16x4.
__global__ __launch_bounds__(256, 2) void out_kernel(
    const float* __restrict__ ctxp, const float* __restrict__ WoR,
    const float* __restrict__ bo, float* __restrict__ out)
{
    const int r0 = blockIdx.x * 64;
    const int c0 = blockIdx.y * 256;
    const int tid = threadIdx.x;
    const int cq  = tid & 63;      // cols c0 + cq*4 .. +3
    const int rid = tid >> 6;      // rows rid*16 + i

    __shared__ float ctxT[64][68];   // transposed [d][row], padded

    #pragma unroll
    for (int i = 0; i < 4; ++i) {
        int f = tid + i * 256;       // 0..1023
        int r = f >> 4, d4 = f & 15;
        size_t base = (size_t)(r0 + r) * DH + d4 * 4;
        float4 a = *(const float4*)&ctxp[base];
        #pragma unroll
        for (int s = 1; s < NSPLIT; ++s) {
            float4 p = *(const float4*)&ctxp[(size_t)s * NN * DH + base];
            a.x += p.x; a.y += p.y; a.z += p.z; a.w += p.w;
        }
        ctxT[d4*4+0][r] = a.x; ctxT[d4*4+1][r] = a.y;
        ctxT[d4*4+2][r] = a.z; ctxT[d4*4+3][r] = a.w;
    }
    __syncthreads();

    float4 bias = *(const float4*)&bo[c0 + cq * 4];
    float acc[16][4];
    #pragma unroll
    for (int i = 0; i < 16; ++i) {
        acc[i][0] = bias.x; acc[i][1] = bias.y; acc[i][2] = bias.z; acc[i][3] = bias.w;
    }

    for (int d = 0; d < 64; ++d) {
        float4 w4 = *(const float4*)&WoR[(size_t)d * DD + c0 + cq * 4];
        #pragma unroll
        for (int ii = 0; ii < 4; ++ii) {
            float4 a4 = *(const float4*)&ctxT[d][rid * 16 + ii * 4];   // broadcast
            acc[ii*4+0][0] += a4.x * w4.x; acc[ii*4+0][1] += a4.x * w4.y;
            acc[ii*4+0][2] += a4.x * w4.z; acc[ii*4+0][3] += a4.x * w4.w;
            acc[ii*4+1][0] += a4.y * w4.x; acc[ii*4+1][1] += a4.y * w4.y;
            acc[ii*4+1][2] += a4.y * w4.z; acc[ii*4+1][3] += a4.y * w4.w;
            acc[ii*4+2][0] += a4.z * w4.x; acc[ii*4+2][1] += a4.z * w4.y;
            acc[ii*4+2][2] += a4.z * w4.z; acc[ii*4+2][3] += a4.z * w4.w;
            acc[ii*4+3][0] += a4.w * w4.x; acc[ii*4+3][1] += a4.w * w4.y;
            acc[ii*4+3][2] += a4.w * w4.z; acc[ii*4+3][3] += a4.w * w4.w;
        }
    }
    #pragma unroll
    for (int i = 0; i < 16; ++i)
        *(float4*)&out[(size_t)(r0 + rid * 16 + i) * DD + c0 + cq * 4] =
            make_float4(acc[i][0], acc[i][1], acc[i][2], acc[i][3]);
}

// ---------------- launch ----------------
extern "C" void kernel_launch(void* const* d_in, const int* in_sizes, int n_in,
                              void* d_out, int out_size, void* d_ws, size_t ws_size,
                              hipStream_t stream)
{
    const float* Q  = (const float*)d_in[0];
    const float* K  = (const float*)d_in[1];
    const float* V  = (const float*)d_in[2];
    const float* Wq = (const float*)d_in[3];
    const float* bq = (const float*)d_in[4];
    const float* Wk = (const float*)d_in[5];
    const float* bk = (const float*)d_in[6];
    const float* Wv = (const float*)d_in[7];
    const float* bv = (const float*)d_in[8];
    const float* Wo = (const float*)d_in[9];
    const float* bo = (const float*)d_in[10];
    float* out = (float*)d_out;

    float* ws = (float*)d_ws;
    float* qv      = ws + OFF_Q;
    float* kv      = ws + OFF_K;
    float* vv      = ws + OFF_V;
    float* ctxp    = ws + OFF_CTXP;
    float* colsum  = ws + OFF_CS;
    float* colsum_p= ws + OFF_CSP;
    float* vp      = ws + OFF_VP;
    float* WoR     = ws + OFF_WOR;
    float* E       = ws + OFF_E;

    // how many batches of E fit in the remaining workspace (fallback chunking)
    size_t wsf = ws_size / 4;
    int nb = 1;
    if (wsf > OFF_E) {
        size_t fit = (wsf - OFF_E) / ((size_t)SSZ * SSZ);
        nb = fit >= 4 ? 4 : (fit >= 1 ? (int)fit : 1);
    }

    // No atomics anywhere -> no memset needed; every ws buffer is fully
    // written before it is read.

    proj_kernel<<<dim3(NN / 64, 3), 256, 0, stream>>>(Q, K, V, Wq, bq, Wk, bk, Wv, bv, qv);
    wored_kernel<<<dim3((DH * DD) / 256), 256, 0, stream>>>(Wo, WoR);

    for (int b0 = 0; b0 < BB; b0 += nb) {
        int nbg = (BB - b0) < nb ? (BB - b0) : nb;
        scores_kernel<<<dim3(NQB, 16, nbg), 256, 0, stream>>>(qv, kv, E, colsum_p, b0);
        colsum_reduce_kernel<<<dim3(nbg * (SSZ / 256)), 256, 0, stream>>>(colsum_p, colsum, b0);
        vprime_kernel<<<dim3(nbg * (SSZ * DH / 256)), 256, 0, stream>>>(vv, colsum, vp, b0);
        ctx_kernel<<<dim3(16, NSPLIT, nbg), 256, 0, stream>>>(E, vp, ctxp, b0);
    }
    out_kernel<<<dim3(NN / 64, 4), 256, 0, stream>>>(ctxp, WoR, bo, out);
}

// Round 14
// 313.029 us; speedup vs baseline: 3.6289x; 1.0505x over previous
//
#include <hip/hip_runtime.h>

#define BB 4
#define SSZ 2048
#define DD 1024
#define DH 64
#define NN (BB*SSZ)          // 8192 rows total
#define NSPLIT 4             // ctx split-K partial slabs
#define NQB 16               // q-blocks in scores (SSZ/128)

// ---------------- ws layout (in floats) ----------------
// q [NN][DH], k [NN][DH], v [NN][DH], ctxp [NSPLIT][NN][DH], colsum [NN],
// colsum_p [NQB][BB][SSZ], vp [NN][DH], WoR [DH][DD], E [nb][SSZ][SSZ]
#define OFF_Q    ((size_t)0)
#define OFF_K    ((size_t)NN*DH)
#define OFF_V    ((size_t)2*NN*DH)
#define OFF_CTXP ((size_t)3*NN*DH)
#define OFF_CS   (OFF_CTXP + (size_t)NSPLIT*NN*DH)
#define OFF_CSP  (OFF_CS + NN)
#define OFF_VP   (OFF_CSP + (size_t)NQB*BB*SSZ)
#define OFF_WOR  (OFF_VP + (size_t)NN*DH)
#define OFF_E    (OFF_WOR + (size_t)DH*DD)

// NOTE: parameter names must NOT collide with float4 member names (x,y,z,w) --
// the preprocessor substitutes params in member-access position too.
#define FMA4(A_, S_, W_) \
    A_.x += (S_) * (W_).x; A_.y += (S_) * (W_).y; \
    A_.z += (S_) * (W_).z; A_.w += (S_) * (W_).w;

// ---------------- projections: q/k/v = X @ W + b ----------------
// grid (NN/32, 3), block 256. Tile 32 rows x 64 cols, full K, no atomics.
// 768 blocks (~3/CU -> ~12 waves/CU) vs prior 384 (13.6% occupancy was the
// measured bottleneck: VALUBusy 35%, HBM 7.7%). Register-prefetch
// double-buffering: load chunk k+1 global->reg while computing chunk k.
__global__ __launch_bounds__(256) void proj_kernel(
    const float* __restrict__ Q, const float* __restrict__ K, const float* __restrict__ V,
    const float* __restrict__ Wq, const float* __restrict__ bq,
    const float* __restrict__ Wk, const float* __restrict__ bk,
    const float* __restrict__ Wv, const float* __restrict__ bv,
    float* __restrict__ qkv)
{
    const int mat = blockIdx.y;
    const float* X    = mat == 0 ? Q  : (mat == 1 ? K  : V);
    const float* W    = mat == 0 ? Wq : (mat == 1 ? Wk : Wv);
    const float* bias = mat == 0 ? bq : (mat == 1 ? bk : bv);
    float* out = qkv + (size_t)mat * NN * DH;

    const int tid  = threadIdx.x;
    const int row0 = blockIdx.x * 32;
    const int tc = tid & 15;   // cols tc*4 .. +3
    const int tr = tid >> 4;   // rows tr*2 .. +1

    __shared__ float Xs[32 * 36];   // 32 rows x 32 k, stride 36
    __shared__ float Ws[32 * 64];   // 32 k x 64 cols

    // per-thread staging assignments
    const int xr = tid >> 3, xc4 = tid & 7;          // X: 1 float4 (row xr, k xc4*4)
    const int wr0 = tid >> 4, wc4 = tid & 15;        // W: 2 float4 (rows wr0, wr0+16)

    // prefetch chunk 0 into registers
    float4 xpre = *(const float4*)&X[(size_t)(row0 + xr) * DD + xc4 * 4];
    float4 wpre0 = *(const float4*)&W[(size_t)(wr0)      * DH + wc4 * 4];
    float4 wpre1 = *(const float4*)&W[(size_t)(wr0 + 16) * DH + wc4 * 4];

    float4 bias4 = *(const float4*)&bias[tc * 4];
    float4 acc[2];
    acc[0] = bias4; acc[1] = bias4;

    for (int k0 = 0; k0 < DD; k0 += 32) {
        // write prefetched chunk into LDS
        *(float4*)&Xs[xr * 36 + xc4 * 4] = xpre;
        *(float4*)&Ws[wr0 * 64 + wc4 * 4]       = wpre0;
        *(float4*)&Ws[(wr0 + 16) * 64 + wc4 * 4] = wpre1;
        __syncthreads();
        // issue next chunk's global loads (latency hidden under compute)
        if (k0 + 32 < DD) {
            xpre  = *(const float4*)&X[(size_t)(row0 + xr) * DD + k0 + 32 + xc4 * 4];
            wpre0 = *(const float4*)&W[(size_t)(k0 + 32 + wr0)      * DH + wc4 * 4];
            wpre1 = *(const float4*)&W[(size_t)(k0 + 32 + wr0 + 16) * DH + wc4 * 4];
        }
        #pragma unroll
        for (int kg = 0; kg < 32; kg += 4) {
            float4 xv0 = *(const float4*)&Xs[(tr * 2 + 0) * 36 + kg];
            float4 xv1 = *(const float4*)&Xs[(tr * 2 + 1) * 36 + kg];
            float4 w0 = *(const float4*)&Ws[(kg + 0) * 64 + tc * 4];
            float4 w1 = *(const float4*)&Ws[(kg + 1) * 64 + tc * 4];
            float4 w2 = *(const float4*)&Ws[(kg + 2) * 64 + tc * 4];
            float4 w3 = *(const float4*)&Ws[(kg + 3) * 64 + tc * 4];
            FMA4(acc[0], xv0.x, w0); FMA4(acc[0], xv0.y, w1);
            FMA4(acc[0], xv0.z, w2); FMA4(acc[0], xv0.w, w3);
            FMA4(acc[1], xv1.x, w0); FMA4(acc[1], xv1.y, w1);
            FMA4(acc[1], xv1.z, w2); FMA4(acc[1], xv1.w, w3);
        }
        __syncthreads();   // LDS consumed; safe to overwrite next iteration
    }
    #pragma unroll
    for (int i = 0; i < 2; ++i)
        *(float4*)&out[(size_t)(row0 + tr * 2 + i) * DH + tc * 4] = acc[i];
}

// ---------------- WoR[d][m] = sum_h Wo[h*64+d][m] ----------------
__global__ __launch_bounds__(256) void wored_kernel(
    const float* __restrict__ Wo, float* __restrict__ WoR)
{
    int idx = blockIdx.x * 256 + threadIdx.x;   // 0..65535
    int d = idx >> 10;
    int m = idx & 1023;
    float s = 0.f;
    #pragma unroll
    for (int h = 0; h < 16; ++h) s += Wo[(size_t)(h * DH + d) * DD + m];
    WoR[idx] = s;
}

// ---------------- scores: E = exp(q.k/8), per-block colsum partials ----------------
// grid (NQB,16,nbg), block 256, tile 128x128, micro 8x(4+4).
// Lane owns cols tc*4+{0..3} and 64+tc*4+{0..3}: both E stores are
// lane-contiguous 256B runs (full-sector writes). NO atomics: per-thread
// column sums -> LDS reduce over the 16 row-groups -> one store per column.
__global__ __launch_bounds__(256, 2) void scores_kernel(
    const float* __restrict__ qv, const float* __restrict__ kv,
    float* __restrict__ E, float* __restrict__ colsum_p, int b0)
{
    const int b  = b0 + blockIdx.z;
    const int qb = blockIdx.x;
    const int q0 = qb * 128;
    const int k0 = blockIdx.y * 128;
    const int tid = threadIdx.x;
    const int tc = tid & 15, tr = tid >> 4;

    __shared__ float qs[128 * 64];
    __shared__ float ks[128 * 64];

    const float* qg = qv + ((size_t)b * SSZ + q0) * DH;
    const float* kg = kv + ((size_t)b * SSZ + k0) * DH;
    #pragma unroll
    for (int i = 0; i < 8; ++i) {
        int f = tid + i * 256;           // 0..2047
        int r = f >> 4, d4 = f & 15;
        int sw = (r >> 3) & 7;
        float4 a = *(const float4*)&qg[(size_t)r * DH + d4 * 4];
        *(float4*)&qs[r * 64 + ((d4 ^ sw) << 2)] = a;
        float4 c = *(const float4*)&kg[(size_t)r * DH + d4 * 4];
        *(float4*)&ks[r * 64 + ((d4 ^ sw) << 2)] = c;
    }
    __syncthreads();

    float acc[8][8];
    #pragma unroll
    for (int i = 0; i < 8; ++i)
        #pragma unroll
        for (int j = 0; j < 8; ++j) acc[i][j] = 0.f;

    for (int d0 = 0; d0 < 64; d0 += 4) {
        float4 qf[8], kf[8];
        #pragma unroll
        for (int i = 0; i < 8; ++i) {
            int r = tr * 8 + i;
            qf[i] = *(const float4*)&qs[r * 64 + ((((d0 >> 2)) ^ ((r >> 3) & 7)) << 2)];
        }
        #pragma unroll
        for (int j = 0; j < 8; ++j) {
            int r = (j < 4) ? (tc * 4 + j) : (64 + tc * 4 + (j - 4));   // owned col
            kf[j] = *(const float4*)&ks[r * 64 + ((((d0 >> 2)) ^ ((r >> 3) & 7)) << 2)];
        }
        #pragma unroll
        for (int i = 0; i < 8; ++i)
            #pragma unroll
            for (int j = 0; j < 8; ++j)
                acc[i][j] += qf[i].x * kf[j].x + qf[i].y * kf[j].y
                           + qf[i].z * kf[j].z + qf[i].w * kf[j].w;
    }

    // epilogue: exp(score/8) -> E (coalesced), per-thread column sums
    float cs[8];
    #pragma unroll
    for (int j = 0; j < 8; ++j) cs[j] = 0.f;
    float* Eb = E + (size_t)blockIdx.z * SSZ * SSZ;   // local-batch E slab
    #pragma unroll
    for (int i = 0; i < 8; ++i) {
        float e[8];
        #pragma unroll
        for (int j = 0; j < 8; ++j) {
            e[j] = __expf(acc[i][j] * 0.125f);
            cs[j] += e[j];
        }
        float* dst = Eb + (size_t)(q0 + tr * 8 + i) * SSZ + k0;
        *(float4*)&dst[tc * 4]      = make_float4(e[0], e[1], e[2], e[3]);
        *(float4*)&dst[64 + tc * 4] = make_float4(e[4], e[5], e[6], e[7]);
    }

    // LDS reduce cs over the 16 tr-groups -> one plain store per column
    __syncthreads();                       // everyone done reading qs
    float* red = qs;                       // reuse: [16][132] padded
    #pragma unroll
    for (int j = 0; j < 8; ++j) {
        int c = (j < 4) ? (tc * 4 + j) : (64 + tc * 4 + (j - 4));
        red[tr * 132 + c] = cs[j];
    }
    __syncthreads();
    if (tid < 128) {
        float s = 0.f;
        #pragma unroll
        for (int t = 0; t < 16; ++t) s += red[t * 132 + tid];
        colsum_p[((size_t)qb * BB + b) * SSZ + k0 + tid] = s;
    }
}

// ---------------- colsum[b][s] = sum_qb colsum_p[qb][b][s] ----------------
__global__ __launch_bounds__(256) void colsum_reduce_kernel(
    const float* __restrict__ colsum_p, float* __restrict__ colsum, int b0)
{
    int idx = blockIdx.x * 256 + threadIdx.x;   // < nbg*SSZ
    int lb = idx / SSZ;
    int s  = idx - lb * SSZ;
    int b  = b0 + lb;
    float sum = 0.f;
    #pragma unroll
    for (int qb = 0; qb < NQB; ++qb)
        sum += colsum_p[((size_t)qb * BB + b) * SSZ + s];
    colsum[(size_t)b * SSZ + s] = sum;
}

// ---------------- vp = v / colsum ----------------
__global__ __launch_bounds__(256) void vprime_kernel(
    const float* __restrict__ v, const float* __restrict__ colsum,
    float* __restrict__ vp, int b0)
{
    int idx = blockIdx.x * 256 + threadIdx.x;        // < nbg*SSZ*DH
    int lb  = idx / (SSZ * DH);
    int rem = idx - lb * (SSZ * DH);
    size_t g = (size_t)(b0 + lb) * SSZ * DH + rem;
    vp[g] = v[g] / colsum[(size_t)(b0 + lb) * SSZ + (rem >> 6)];
}

// ---------------- ctx partials: ctxp[s] = E[:, s-chunk] @ vp[s-chunk] ----------------
// grid (16, NSPLIT, nbg), block 256, q-tile 128, k-chunk 512, micro 8x4.
// Plain stores to per-split slabs -- NO atomics.
#define C_KC (SSZ / NSPLIT)   // 512
__global__ __launch_bounds__(256, 2) void ctx_kernel(
    const float* __restrict__ E, const float* __restrict__ vp,
    float* __restrict__ ctxp, int b0)
{
    const int lb = blockIdx.z;
    const int b  = b0 + lb;
    const int split = blockIdx.y;
    const int q0 = blockIdx.x * 128;
    const int kbase = split * C_KC;
    const int tid = threadIdx.x;
    const int tc = tid & 15, tr = tid >> 4;

    __shared__ float Es[128 * 128];   // 64 KB, XOR-swizzled

    const float* Eg  = E  + (size_t)lb * SSZ * SSZ;
    const float* vpg = vp + (size_t)b * SSZ * DH;

    float acc[8][4];
    #pragma unroll
    for (int i = 0; i < 8; ++i)
        #pragma unroll
        for (int j = 0; j < 4; ++j) acc[i][j] = 0.f;

    for (int kk0 = 0; kk0 < C_KC; kk0 += 128) {
        __syncthreads();
        #pragma unroll
        for (int i = 0; i < 16; ++i) {
            int f = tid + i * 256;        // 0..4095
            int r = f >> 5, c4 = f & 31;
            int sw = (r >> 3) & 7;
            float4 a = *(const float4*)&Eg[(size_t)(q0 + r) * SSZ + kbase + kk0 + c4 * 4];
            *(float4*)&Es[r * 128 + ((c4 ^ sw) << 2)] = a;
        }
        __syncthreads();
        for (int k = 0; k < 128; k += 4) {
            float vvf[4][4];
            #pragma unroll
            for (int dd = 0; dd < 4; ++dd) {
                float4 t = *(const float4*)&vpg[(size_t)(kbase + kk0 + k + dd) * DH + tc * 4];
                vvf[dd][0] = t.x; vvf[dd][1] = t.y; vvf[dd][2] = t.z; vvf[dd][3] = t.w;
            }
            #pragma unroll
            for (int i = 0; i < 8; ++i) {
                int r = tr * 8 + i;
                float4 e4 = *(const float4*)&Es[r * 128 + ((((k >> 2)) ^ ((r >> 3) & 7)) << 2)];
                #pragma unroll
                for (int j = 0; j < 4; ++j)
                    acc[i][j] += e4.x * vvf[0][j] + e4.y * vvf[1][j]
                               + e4.z * vvf[2][j] + e4.w * vvf[3][j];
            }
        }
    }
    float* cg = ctxp + (size_t)split * NN * DH + (size_t)b * SSZ * DH;
    #pragma unroll
    for (int i = 0; i < 8; ++i)
        *(float4*)&cg[(size_t)(q0 + tr * 8 + i) * DH + tc * 4] =
            make_float4(acc[i][0], acc[i][1], acc[i][2], acc[i][3]);
}

// ---------------- out = (sum_s ctxp[s]) @ WoR + bo ----------------
// grid (NN/64, 4), block 256. tile 64 rows x 256 cols, micro 16x4.
__global__ __launch_bounds__(256, 2) void out_kernel(
    const float* __restrict__ ctxp, const float* __restrict__ WoR,
    const float* __restrict__ bo, float* __restrict__ out)
{
    const int r0 = blockIdx.x * 64;
    const int c0 = blockIdx.y * 256;
    const int tid = threadIdx.x;
    const int cq  = tid & 63;      // cols c0 + cq*4 .. +3
    const int rid = tid >> 6;      // rows rid*16 + i

    __shared__ float ctxT[64][68];   // transposed [d][row], padded

    #pragma unroll
    for (int i = 0; i < 4; ++i) {
        int f = tid + i * 256;       // 0..1023
        int r = f >> 4, d4 = f & 15;
        size_t base = (size_t)(r0 + r) * DH + d4 * 4;
        float4 a = *(const float4*)&ctxp[base];
        #pragma unroll
        for (int s = 1; s < NSPLIT; ++s) {
            float4 p = *(const float4*)&ctxp[(size_t)s * NN * DH + base];
            a.x += p.x; a.y += p.y; a.z += p.z; a.w += p.w;
        }
        ctxT[d4*4+0][r] = a.x; ctxT[d4*4+1][r] = a.y;
        ctxT[d4*4+2][r] = a.z; ctxT[d4*4+3][r] = a.w;
    }
    __syncthreads();

    float4 bias = *(const float4*)&bo[c0 + cq * 4];
    float acc[16][4];
    #pragma unroll
    for (int i = 0; i < 16; ++i) {
        acc[i][0] = bias.x; acc[i][1] = bias.y; acc[i][2] = bias.z; acc[i][3] = bias.w;
    }

    for (int d = 0; d < 64; ++d) {
        float4 w4 = *(const float4*)&WoR[(size_t)d * DD + c0 + cq * 4];
        #pragma unroll
        for (int ii = 0; ii < 4; ++ii) {
            float4 a4 = *(const float4*)&ctxT[d][rid * 16 + ii * 4];   // broadcast
            acc[ii*4+0][0] += a4.x * w4.x; acc[ii*4+0][1] += a4.x * w4.y;
            acc[ii*4+0][2] += a4.x * w4.z; acc[ii*4+0][3] += a4.x * w4.w;
            acc[ii*4+1][0] += a4.y * w4.x; acc[ii*4+1][1] += a4.y * w4.y;
            acc[ii*4+1][2] += a4.y * w4.z; acc[ii*4+1][3] += a4.y * w4.w;
            acc[ii*4+2][0] += a4.z * w4.x; acc[ii*4+2][1] += a4.z * w4.y;
            acc[ii*4+2][2] += a4.z * w4.z; acc[ii*4+2][3] += a4.z * w4.w;
            acc[ii*4+3][0] += a4.w * w4.x; acc[ii*4+3][1] += a4.w * w4.y;
            acc[ii*4+3][2] += a4.w * w4.z; acc[ii*4+3][3] += a4.w * w4.w;
        }
    }
    #pragma unroll
    for (int i = 0; i < 16; ++i)
        *(float4*)&out[(size_t)(r0 + rid * 16 + i) * DD + c0 + cq * 4] =
            make_float4(acc[i][0], acc[i][1], acc[i][2], acc[i][3]);
}

// ---------------- launch ----------------
extern "C" void kernel_launch(void* const* d_in, const int* in_sizes, int n_in,
                              void* d_out, int out_size, void* d_ws, size_t ws_size,
                              hipStream_t stream)
{
    const float* Q  = (const float*)d_in[0];
    const float* K  = (const float*)d_in[1];
    const float* V  = (const float*)d_in[2];
    const float* Wq = (const float*)d_in[3];
    const float* bq = (const float*)d_in[4];
    const float* Wk = (const float*)d_in[5];
    const float* bk = (const float*)d_in[6];
    const float* Wv = (const float*)d_in[7];
    const float* bv = (const float*)d_in[8];
    const float* Wo = (const float*)d_in[9];
    const float* bo = (const float*)d_in[10];
    float* out = (float*)d_out;

    float* ws = (float*)d_ws;
    float* qv      = ws + OFF_Q;
    float* kv      = ws + OFF_K;
    float* vv      = ws + OFF_V;
    float* ctxp    = ws + OFF_CTXP;
    float* colsum  = ws + OFF_CS;
    float* colsum_p= ws + OFF_CSP;
    float* vp      = ws + OFF_VP;
    float* WoR     = ws + OFF_WOR;
    float* E       = ws + OFF_E;

    // how many batches of E fit in the remaining workspace (fallback chunking)
    size_t wsf = ws_size / 4;
    int nb = 1;
    if (wsf > OFF_E) {
        size_t fit = (wsf - OFF_E) / ((size_t)SSZ * SSZ);
        nb = fit >= 4 ? 4 : (fit >= 1 ? (int)fit : 1);
    }

    // No atomics anywhere -> no memset needed; every ws buffer is fully
    // written before it is read.

    proj_kernel<<<dim3(NN / 32, 3), 256, 0, stream>>>(Q, K, V, Wq, bq, Wk, bk, Wv, bv, qv);
    wored_kernel<<<dim3((DH * DD) / 256), 256, 0, stream>>>(Wo, WoR);

    for (int b0 = 0; b0 < BB; b0 += nb) {
        int nbg = (BB - b0) < nb ? (BB - b0) : nb;
        scores_kernel<<<dim3(NQB, 16, nbg), 256, 0, stream>>>(qv, kv, E, colsum_p, b0);
        colsum_reduce_kernel<<<dim3(nbg * (SSZ / 256)), 256, 0, stream>>>(colsum_p, colsum, b0);
        vprime_kernel<<<dim3(nbg * (SSZ * DH / 256)), 256, 0, stream>>>(vv, colsum, vp, b0);
        ctx_kernel<<<dim3(16, NSPLIT, nbg), 256, 0, stream>>>(E, vp, ctxp, b0);
    }
    out_kernel<<<dim3(NN / 64, 4), 256, 0, stream>>>(ctxp, WoR, bo, out);
}